// Round 9
// baseline (675.748 us; speedup 1.0000x reference)
//
#include <hip/hip_runtime.h>
#include <hip/hip_bf16.h>
#include <cstdint>

namespace {

constexpr int Bn = 2, Sn = 2048, Hn = 3072, NQn = 24, NKVn = 8, HDn = 128;
constexpr int LDQKV = NQn * HDn + 2 * NKVn * HDn;  // 5120
constexpr int KCOLo = NQn * HDn;                   // 3072
constexpr int VCOLo = KCOLo + NKVn * HDn;          // 4096

typedef __attribute__((ext_vector_type(8))) __bf16 bf16x8;
typedef __attribute__((ext_vector_type(4))) float f32x4;
typedef __attribute__((ext_vector_type(4))) unsigned short u16x4;

__device__ __forceinline__ unsigned short f2bf(float f) {
  union { float f; unsigned u; } v; v.f = f;
  return (unsigned short)((v.u + 0x7fffu + ((v.u >> 16) & 1u)) >> 16);
}
__device__ __forceinline__ float bf2f(unsigned short u) {
  union { unsigned u; float f; } v; v.u = ((unsigned)u) << 16;
  return v.f;
}
__device__ __forceinline__ void gload_lds16(const void* g, void* l) {
  __builtin_amdgcn_global_load_lds(
      (__attribute__((address_space(1))) void*)(uintptr_t)g,
      (__attribute__((address_space(3))) void*)(uintptr_t)l, 16, 0, 0);
}

// ---------------- RoPE cos/sin table: [S][48] each ----------------
__global__ void build_rope_tab(float* __restrict__ cosT, float* __restrict__ sinT) {
  int idx = blockIdx.x * 256 + threadIdx.x;
  if (idx >= Sn * 48) return;
  int s = idx / 48, i = idx % 48;
  float invf = exp2f(-(float)i * (13.287712379549449f / 48.f));
  float f = (float)s * invf;
  cosT[idx] = cosf(f);
  sinT[idx] = sinf(f);
}

// ---------------- f32 -> bf16 elementwise ----------------
__global__ void cvt_f32_bf16(const float* __restrict__ in, unsigned short* __restrict__ out, int n) {
  int i = (blockIdx.x * 256 + threadIdx.x) * 4;
  int stride = gridDim.x * 256 * 4;
  for (; i < n; i += stride) {
    float4 v = *(const float4*)&in[i];
    u16x4 o;
    o[0] = f2bf(v.x); o[1] = f2bf(v.y); o[2] = f2bf(v.z); o[3] = f2bf(v.w);
    *(u16x4*)&out[i] = o;
  }
}

// ---------------- transpose + convert: in f32 [K][N] -> out bf16 [N][K] ----------------
__global__ void transpose_cvt(const float* __restrict__ in, unsigned short* __restrict__ out,
                              int K, int N) {
  __shared__ float tile[32][33];
  int bx = blockIdx.x * 32;  // N
  int by = blockIdx.y * 32;  // K
  int tx = threadIdx.x & 31, ty = threadIdx.x >> 5;
#pragma unroll
  for (int r = ty; r < 32; r += 8)
    tile[r][tx] = in[(size_t)(by + r) * N + bx + tx];
  __syncthreads();
#pragma unroll
  for (int r = ty; r < 32; r += 8)
    out[(size_t)(bx + r) * K + by + tx] = f2bf(tile[tx][r]);
}

// ---------------- V pre-transpose: QKV V-cols -> VT[(b*NKV+kv)*HD + hd][s] ----------------
__global__ void transpose_v(const unsigned short* __restrict__ QKV, unsigned short* __restrict__ VT) {
  __shared__ unsigned short tile[32][33];
  int s0 = blockIdx.x * 32;
  int b = blockIdx.y >> 5;
  int vc0 = (blockIdx.y & 31) * 32;  // 0..992 within the 1024 V cols of batch b
  int tx = threadIdx.x & 31, ty = threadIdx.x >> 5;
#pragma unroll
  for (int r = ty; r < 32; r += 8)
    tile[r][tx] = QKV[(size_t)(b * Sn + s0 + r) * LDQKV + VCOLo + vc0 + tx];
  __syncthreads();
#pragma unroll
  for (int r = ty; r < 32; r += 8)
    VT[(size_t)(b * (NKVn * HDn) + vc0 + r) * Sn + s0 + tx] = tile[tx][r];
}

// ---------------- 256x256 TN GEMM, BK=64, 8 waves, counted-vmcnt pipeline ----------------
// C[M][N] = A[M][K] * B[N][K]^T. LDS tiles XOR-swizzled (chunk pos = j ^ (row&7))
// via pre-swizzled global source (linear gload_lds dest). Raw s_barrier + vmcnt(8):
// loads for tile t+1 stay in flight while computing tile t (no drain-0).
template <int BF16OUT>
__launch_bounds__(512, 1)
__global__ void gemm256(const unsigned short* __restrict__ A, const unsigned short* __restrict__ Bm,
                        void* __restrict__ Cout, int M, int N, int K) {
  __shared__ unsigned short Al[2][256 * 64];
  __shared__ unsigned short Bl[2][256 * 64];
  const int t = threadIdx.x;
  const int lane = t & 63;
  const int w = t >> 6;              // 8 waves: 2 (M) x 4 (N)
  const int wm = w >> 2, wn = w & 3;
  const int l15 = lane & 15, lq = lane >> 4;
  const int brow = blockIdx.y * 256, bcol = blockIdx.x * 256;
  const unsigned short* Ab = A + (size_t)brow * K;
  const unsigned short* Bb = Bm + (size_t)bcol * K;
  f32x4 acc[8][4] = {};
  const int nT = K >> 6;

  auto stage = [&](int kt, int buf) {
#pragma unroll
    for (int it = 0; it < 4; ++it) {
      int c = it * 512 + t;
      int row = c >> 3, pos = c & 7;
      int j = pos ^ (row & 7);
      gload_lds16(Ab + (size_t)row * K + kt * 64 + j * 8, (char*)&Al[buf][0] + c * 16);
    }
#pragma unroll
    for (int it = 0; it < 4; ++it) {
      int c = it * 512 + t;
      int row = c >> 3, pos = c & 7;
      int j = pos ^ (row & 7);
      gload_lds16(Bb + (size_t)row * K + kt * 64 + j * 8, (char*)&Bl[buf][0] + c * 16);
    }
  };

  stage(0, 0);
  stage(1, 1);
  for (int kt = 0; kt < nT; ++kt) {
    if (kt + 1 < nT) asm volatile("s_waitcnt vmcnt(8)" ::: "memory");
    else             asm volatile("s_waitcnt vmcnt(0)" ::: "memory");
    __builtin_amdgcn_s_barrier();      // all waves: tile kt landed
    __builtin_amdgcn_sched_barrier(0);
    const unsigned short* Abl = &Al[kt & 1][0];
    const unsigned short* Bbl = &Bl[kt & 1][0];
#pragma unroll
    for (int ks = 0; ks < 2; ++ks) {
      bf16x8 aF[8], bF[4];
      const int j = ks * 4 + lq;  // logical 16B chunk (k-offset lq*8 within ks*32)
#pragma unroll
      for (int m = 0; m < 8; ++m) {
        int row = wm * 128 + m * 16 + l15;
        aF[m] = *(const bf16x8*)&Abl[row * 64 + (j ^ (row & 7)) * 8];
      }
#pragma unroll
      for (int n = 0; n < 4; ++n) {
        int row = wn * 64 + n * 16 + l15;
        bF[n] = *(const bf16x8*)&Bbl[row * 64 + (j ^ (row & 7)) * 8];
      }
      __builtin_amdgcn_s_setprio(1);
#pragma unroll
      for (int m = 0; m < 8; ++m)
#pragma unroll
        for (int n = 0; n < 4; ++n)
          acc[m][n] = __builtin_amdgcn_mfma_f32_16x16x32_bf16(aF[m], bF[n], acc[m][n], 0, 0, 0);
      __builtin_amdgcn_s_setprio(0);
    }
    asm volatile("s_waitcnt lgkmcnt(0)" ::: "memory");
    __builtin_amdgcn_s_barrier();      // all waves done reading buf (kt&1)
    __builtin_amdgcn_sched_barrier(0);
    if (kt + 2 < nT) stage(kt + 2, kt & 1);  // safe: last read of this buf was tile kt
  }

  const int lr = lq * 4;
  if (BF16OUT) {
    unsigned short* C = (unsigned short*)Cout;
#pragma unroll
    for (int m = 0; m < 8; ++m) {
      int row = brow + wm * 128 + m * 16 + lr;
#pragma unroll
      for (int n = 0; n < 4; ++n) {
        int col = bcol + wn * 64 + n * 16 + l15;
#pragma unroll
        for (int i = 0; i < 4; ++i)
          C[(size_t)(row + i) * N + col] = f2bf(acc[m][n][i]);
      }
    }
  } else {
    float* C = (float*)Cout;
#pragma unroll
    for (int m = 0; m < 8; ++m) {
      int row = brow + wm * 128 + m * 16 + lr;
#pragma unroll
      for (int n = 0; n < 4; ++n) {
        int col = bcol + wn * 64 + n * 16 + l15;
#pragma unroll
        for (int i = 0; i < 4; ++i)
          C[(size_t)(row + i) * N + col] = acc[m][n][i];
      }
    }
  }
}

// ---------------- RoPE in place on QKV [4096][5120] ----------------
__global__ void rope_kernel(unsigned short* __restrict__ QKV, const float* __restrict__ cosT,
                            const float* __restrict__ sinT) {
  int rid = blockIdx.x;
  int s = rid & (Sn - 1);
  unsigned short* row = QKV + (size_t)rid * LDQKV;
  for (int p = threadIdx.x; p < 32 * 48; p += 256) {
    int h = p / 48, i = p % 48;
    int col = (h < NQn) ? h * HDn : KCOLo + (h - NQn) * HDn;
    float c = cosT[s * 48 + i], sn = sinT[s * 48 + i];
    float x1 = bf2f(row[col + i]), x2 = bf2f(row[col + i + 48]);
    row[col + i] = f2bf(x1 * c - x2 * sn);
    row[col + i + 48] = f2bf(x2 * c + x1 * sn);
  }
}

// ---------------- Flash attention (causal, GQA 3:1), double-buffered K/V ----------------
// Swapped-operand QK^T: S = mfma(K, Q) -> lane-local q (col = lane&15) so the
// softmax reduce is in-register + 2 shuffles, and m/l/rescale are scalars.
// grid: (S/64, B*NQ); 256 thr = 4 waves; wave w owns q rows [bq*64+w*16, +16)
__launch_bounds__(256, 2)
__global__ void attn_kernel(const unsigned short* __restrict__ QKV,
                            const unsigned short* __restrict__ VT,
                            unsigned short* __restrict__ O) {
  __shared__ unsigned short Klds[2][64 * 128];  // [kcol][hd] chunks, src pre-swizzled
  __shared__ unsigned short Vlds[2][128 * 64];  // [hd][k] chunks, src pre-swizzled
  __shared__ unsigned short Plds[4][16 * 64];   // per-wave [q][k] swizzled
  const int t = threadIdx.x, lane = t & 63, w = t >> 6;
  const int bq = gridDim.x - 1 - blockIdx.x;  // heavy (many-tile) blocks dispatch first
  const int hid = blockIdx.y;
  const int b = hid / NQn, u = hid % NQn, kv = u / 3;
  const int l15 = lane & 15, lh = lane >> 4;

  bf16x8 qf[4];
  {
    int qrow = bq * 64 + w * 16 + l15;
    const unsigned short* qp = QKV + (size_t)(b * Sn + qrow) * LDQKV + u * HDn;
#pragma unroll
    for (int f = 0; f < 4; ++f) qf[f] = *(const bf16x8*)(qp + f * 32 + lh * 8);
  }
  // lane-local softmax state for q = w*16 + l15 (lanes l15, l15+16, +32, +48 replicate)
  float m_l = -1e30f, l_l = 0.f;
  f32x4 Oa[8] = {};  // O^T: Oa[g][i] = O[q=l15][hd=g*16+lh*4+i]
  const float cscale = 0.08838834764831845f * 1.4426950408889634f;  // 1/sqrt(128)*log2e

  const unsigned short* Kg = QKV + (size_t)(b * Sn) * LDQKV + KCOLo + kv * HDn;
  const unsigned short* Vg = VT + (size_t)(b * NKVn + kv) * HDn * Sn;

  auto stageK = [&](int kt, int buf) {
#pragma unroll
    for (int iter = 0; iter < 4; ++iter) {
      int c = iter * 256 + t;
      int krow = c >> 4, pch = c & 15;
      int hch = (pch & 8) | ((pch & 7) ^ (krow & 7));
      gload_lds16(Kg + (size_t)(kt * 64 + krow) * LDQKV + hch * 8,
                  (char*)&Klds[buf][0] + (iter * 256 + w * 64) * 16);
    }
  };
  auto stageV = [&](int kt, int buf) {
#pragma unroll
    for (int iter = 0; iter < 4; ++iter) {
      int c = iter * 256 + t;
      int hd = c >> 3, p = c & 7;
      int sch = p ^ (hd & 7);
      gload_lds16(Vg + (size_t)hd * Sn + kt * 64 + sch * 8,
                  (char*)&Vlds[buf][0] + (iter * 256 + w * 64) * 16);
    }
  };

  const int nt = bq + 1;
  stageK(0, 0);
  stageV(0, 0);
  __syncthreads();  // drains vmcnt (barrier semantics)

  for (int kt = 0; kt < nt; ++kt) {
    const int cur = kt & 1;
    if (kt + 1 < nt) { stageK(kt + 1, cur ^ 1); stageV(kt + 1, cur ^ 1); }
    const unsigned short* Kb = &Klds[cur][0];
    const unsigned short* Vb = &Vlds[cur][0];
    // QK^T swapped: Sg[g] = S[k=g*16+lh*4+i][q=l15]
    f32x4 Sg[4] = {};
    __builtin_amdgcn_s_setprio(1);
#pragma unroll
    for (int g = 0; g < 4; ++g) {
      int kcol = g * 16 + l15;  // A-row = k
#pragma unroll
      for (int s = 0; s < 4; ++s) {
        int h = s * 4 + lh;
        int p = (h & 8) | ((h & 7) ^ (kcol & 7));
        bf16x8 kf = *(const bf16x8*)&Kb[kcol * 128 + p * 8];
        Sg[g] = __builtin_amdgcn_mfma_f32_16x16x32_bf16(kf, qf[s], Sg[g], 0, 0, 0);
      }
    }
    __builtin_amdgcn_s_setprio(0);
    float P[4][4];
    const bool last = (kt == bq);
    const int qin = w * 16 + l15;
#pragma unroll
    for (int g = 0; g < 4; ++g)
#pragma unroll
      for (int i = 0; i < 4; ++i) {
        float sv = Sg[g][i] * cscale;
        if (last && (g * 16 + lh * 4 + i) > qin) sv = -1e30f;
        P[g][i] = sv;
      }
    // lane-local online softmax (one q per lane)
    float pmax = -1e30f;
#pragma unroll
    for (int g = 0; g < 4; ++g)
#pragma unroll
      for (int i = 0; i < 4; ++i) pmax = fmaxf(pmax, P[g][i]);
    pmax = fmaxf(pmax, __shfl_xor(pmax, 16, 64));
    pmax = fmaxf(pmax, __shfl_xor(pmax, 32, 64));
    float mn = fmaxf(m_l, pmax);
    float rs = exp2f(m_l - mn);
    m_l = mn;
    float ps = 0.f;
#pragma unroll
    for (int g = 0; g < 4; ++g)
#pragma unroll
      for (int i = 0; i < 4; ++i) {
        float e = exp2f(P[g][i] - mn);
        P[g][i] = e;
        ps += e;
      }
    ps += __shfl_xor(ps, 16, 64);
    ps += __shfl_xor(ps, 32, 64);
    l_l = l_l * rs + ps;
#pragma unroll
    for (int g = 0; g < 8; ++g)
#pragma unroll
      for (int i = 0; i < 4; ++i) Oa[g][i] *= rs;
    // P -> per-wave LDS [q=l15][k], packed b64 writes, swizzled by (k>>3)^(q&7)
    unsigned short* pl = Plds[w];
#pragma unroll
    for (int g = 0; g < 4; ++g) {
      int ch = g * 2 + (lh >> 1);
      int pos = ch ^ (l15 & 7);
      u16x4 pk;
#pragma unroll
      for (int i = 0; i < 4; ++i) pk[i] = f2bf(P[g][i]);
      *(u16x4*)&pl[l15 * 64 + pos * 8 + (lh & 1) * 4] = pk;
    }
    // PV swapped: Oa[g] = mfma(V[hd][k], P[k][q]) -> D[hd][q]
    __builtin_amdgcn_s_setprio(1);
#pragma unroll
    for (int kk = 0; kk < 2; ++kk) {
      int ch = kk * 4 + lh;
      bf16x8 pf = *(const bf16x8*)&pl[l15 * 64 + ((ch ^ (l15 & 7)) & 7) * 8];
#pragma unroll
      for (int g = 0; g < 8; ++g) {
        int hd = g * 16 + l15;
        int vpos = (ch ^ (hd & 7)) & 7;
        bf16x8 vf = *(const bf16x8*)&Vb[hd * 64 + vpos * 8];
        Oa[g] = __builtin_amdgcn_mfma_f32_16x16x32_bf16(vf, pf, Oa[g], 0, 0, 0);
      }
    }
    __builtin_amdgcn_s_setprio(0);
    __syncthreads();  // all waves done with buf cur; next-tile loads drained
  }
  // Epilogue: O^T -> O through per-wave scratch in (dead) Klds, coalesced store.
  {
    unsigned short* sc = (unsigned short*)Klds + w * 2176;  // [16 q][136 hd] padded
    float inv = 1.0f / l_l;
#pragma unroll
    for (int g = 0; g < 8; ++g)
#pragma unroll
      for (int i = 0; i < 4; ++i)
        sc[l15 * 136 + g * 16 + lh * 4 + i] = f2bf(Oa[g][i] * inv);
    int q = lane >> 2, a = lane & 3;
    int row = bq * 64 + w * 16 + q;
    unsigned short* op = O + (size_t)(b * Sn + row) * (NQn * HDn) + u * HDn;
    const unsigned short* scr = sc + q * 136;
#pragma unroll
    for (int j = 0; j < 4; ++j) {
      bf16x8 v = *(const bf16x8*)&scr[a * 8 + j * 32];
      *(bf16x8*)&op[a * 8 + j * 32] = v;
    }
  }
}

}  // namespace

extern "C" void kernel_launch(void* const* d_in, const int* in_sizes, int n_in,
                              void* d_out, int out_size, void* d_ws, size_t ws_size,
                              hipStream_t stream) {
  const float* hidden = (const float*)d_in[0];
  // d_in[1] = attention_mask (causal tril) -- implemented analytically
  const float* Wq = (const float*)d_in[2];
  const float* Wk = (const float*)d_in[3];
  const float* Wv = (const float*)d_in[4];
  const float* Wo = (const float*)d_in[5];
  float* out = (float*)d_out;

  // Workspace layout (aliased; same-stream ordering makes each alias safe):
  //   [0)           Xb   (25.2MB)  -- dead after GEMM1; Obuf aliases it
  //   [szXb)        Wqkv (31.5MB)  -- dead after GEMM1; Wob (18.9MB) + VT (8.4MB) alias it
  //   [szXb+szWqkv) QKV  (41.9MB)
  //   [+szQKV)      cosT/sinT (0.8MB)
  char* ws = (char*)d_ws;
  constexpr size_t szXb = (size_t)Bn * Sn * Hn * 2;             // 25165824
  constexpr size_t szWqkv = (size_t)LDQKV * Hn * 2;             // 31457280
  constexpr size_t szWo = (size_t)Hn * Hn * 2;                  // 18874368
  constexpr size_t szVT = (size_t)Bn * NKVn * HDn * Sn * 2;     // 8388608
  constexpr size_t szQKV = (size_t)Bn * Sn * LDQKV * 2;         // 41943040
  constexpr size_t szTab = (size_t)Sn * 48 * 4;                 // 393216
  static_assert(szWo + szVT <= szWqkv, "Wob+VT must fit in Wqkv region");
  constexpr size_t szTotal = szXb + szWqkv + szQKV + 2 * szTab; // 99352576
  if (ws_size < szTotal) return;  // fail cleanly, don't fault

  unsigned short* Xb = (unsigned short*)(ws);
  unsigned short* Obuf = Xb;                                  // alias
  unsigned short* Wqkv = (unsigned short*)(ws + szXb);
  unsigned short* Wob = Wqkv;                                 // alias (after GEMM1)
  unsigned short* VT = (unsigned short*)(ws + szXb + szWo);   // alias (after GEMM1)
  unsigned short* QKV = (unsigned short*)(ws + szXb + szWqkv);
  float* cosT = (float*)(ws + szXb + szWqkv + szQKV);
  float* sinT = (float*)(ws + szXb + szWqkv + szQKV + szTab);

  build_rope_tab<<<(Sn * 48 + 255) / 256, 256, 0, stream>>>(cosT, sinT);
  cvt_f32_bf16<<<3072, 256, 0, stream>>>(hidden, Xb, Bn * Sn * Hn);
  transpose_cvt<<<dim3(96, 96), 256, 0, stream>>>(Wq, Wqkv, Hn, NQn * HDn);
  transpose_cvt<<<dim3(32, 96), 256, 0, stream>>>(Wk, Wqkv + (size_t)KCOLo * Hn, Hn, NKVn * HDn);
  transpose_cvt<<<dim3(32, 96), 256, 0, stream>>>(Wv, Wqkv + (size_t)VCOLo * Hn, Hn, NKVn * HDn);
  gemm256<1><<<dim3(LDQKV / 256, (Bn * Sn) / 256), 512, 0, stream>>>(Xb, Wqkv, QKV,
                                                                     Bn * Sn, LDQKV, Hn);
  // Wqkv and Xb are now dead; reuse their space.
  transpose_cvt<<<dim3(96, 96), 256, 0, stream>>>(Wo, Wob, Hn, Hn);
  transpose_v<<<dim3(Sn / 32, Bn * NKVn * HDn / 32), 256, 0, stream>>>(QKV, VT);
  rope_kernel<<<Bn * Sn, 256, 0, stream>>>(QKV, cosT, sinT);
  attn_kernel<<<dim3(Sn / 64, Bn * NQn), 256, 0, stream>>>(QKV, VT, Obuf);
  gemm256<0><<<dim3(Hn / 256, (Bn * Sn) / 256), 512, 0, stream>>>(Obuf, Wob, out,
                                                                  Bn * Sn, Hn, Hn);
}

// Round 11
// 675.370 us; speedup vs baseline: 1.0006x; 1.0006x over previous
//
#include <hip/hip_runtime.h>
#include <hip/hip_bf16.h>
#include <cstdint>

namespace {

constexpr int Bn = 2, Sn = 2048, Hn = 3072, NQn = 24, NKVn = 8, HDn = 128;
constexpr int LDQKV = NQn * HDn + 2 * NKVn * HDn;  // 5120
constexpr int KCOLo = NQn * HDn;                   // 3072
constexpr int VCOLo = KCOLo + NKVn * HDn;          // 4096

typedef __attribute__((ext_vector_type(8))) __bf16 bf16x8;
typedef __attribute__((ext_vector_type(4))) float f32x4;
typedef __attribute__((ext_vector_type(4))) unsigned short u16x4;

__device__ __forceinline__ unsigned short f2bf(float f) {
  union { float f; unsigned u; } v; v.f = f;
  return (unsigned short)((v.u + 0x7fffu + ((v.u >> 16) & 1u)) >> 16);
}
__device__ __forceinline__ float bf2f(unsigned short u) {
  union { unsigned u; float f; } v; v.u = ((unsigned)u) << 16;
  return v.f;
}
__device__ __forceinline__ void gload_lds16(const void* g, void* l) {
  __builtin_amdgcn_global_load_lds(
      (__attribute__((address_space(1))) void*)(uintptr_t)g,
      (__attribute__((address_space(3))) void*)(uintptr_t)l, 16, 0, 0);
}

// ---------------- RoPE cos/sin table: [S][48] each ----------------
__global__ void build_rope_tab(float* __restrict__ cosT, float* __restrict__ sinT) {
  int idx = blockIdx.x * 256 + threadIdx.x;
  if (idx >= Sn * 48) return;
  int s = idx / 48, i = idx % 48;
  float invf = exp2f(-(float)i * (13.287712379549449f / 48.f));
  float f = (float)s * invf;
  cosT[idx] = cosf(f);
  sinT[idx] = sinf(f);
}

// ---------------- f32 -> bf16 elementwise ----------------
__global__ void cvt_f32_bf16(const float* __restrict__ in, unsigned short* __restrict__ out, int n) {
  int i = (blockIdx.x * 256 + threadIdx.x) * 4;
  int stride = gridDim.x * 256 * 4;
  for (; i < n; i += stride) {
    float4 v = *(const float4*)&in[i];
    u16x4 o;
    o[0] = f2bf(v.x); o[1] = f2bf(v.y); o[2] = f2bf(v.z); o[3] = f2bf(v.w);
    *(u16x4*)&out[i] = o;
  }
}

// ---------------- transpose + convert: in f32 [K][N] -> out bf16 [N][K] ----------------
__global__ void transpose_cvt(const float* __restrict__ in, unsigned short* __restrict__ out,
                              int K, int N) {
  __shared__ float tile[32][33];
  int bx = blockIdx.x * 32;  // N
  int by = blockIdx.y * 32;  // K
  int tx = threadIdx.x & 31, ty = threadIdx.x >> 5;
#pragma unroll
  for (int r = ty; r < 32; r += 8)
    tile[r][tx] = in[(size_t)(by + r) * N + bx + tx];
  __syncthreads();
#pragma unroll
  for (int r = ty; r < 32; r += 8)
    out[(size_t)(bx + r) * K + by + tx] = f2bf(tile[tx][r]);
}

// ---------------- V pre-transpose: QKV V-cols -> VT[(b*NKV+kv)*HD + hd][s] ----------------
__global__ void transpose_v(const unsigned short* __restrict__ QKV, unsigned short* __restrict__ VT) {
  __shared__ unsigned short tile[32][33];
  int s0 = blockIdx.x * 32;
  int b = blockIdx.y >> 5;
  int vc0 = (blockIdx.y & 31) * 32;  // 0..992 within the 1024 V cols of batch b
  int tx = threadIdx.x & 31, ty = threadIdx.x >> 5;
#pragma unroll
  for (int r = ty; r < 32; r += 8)
    tile[r][tx] = QKV[(size_t)(b * Sn + s0 + r) * LDQKV + VCOLo + vc0 + tx];
  __syncthreads();
#pragma unroll
  for (int r = ty; r < 32; r += 8)
    VT[(size_t)(b * (NKVn * HDn) + vc0 + r) * Sn + s0 + tx] = tile[tx][r];
}

// ---------------- 256x256 TN GEMM, BK=64, 8 waves, counted-vmcnt pipeline ----------------
template <int BF16OUT>
__launch_bounds__(512, 1)
__global__ void gemm256(const unsigned short* __restrict__ A, const unsigned short* __restrict__ Bm,
                        void* __restrict__ Cout, int M, int N, int K) {
  __shared__ unsigned short Al[2][256 * 64];
  __shared__ unsigned short Bl[2][256 * 64];
  const int t = threadIdx.x;
  const int lane = t & 63;
  const int w = t >> 6;              // 8 waves: 2 (M) x 4 (N)
  const int wm = w >> 2, wn = w & 3;
  const int l15 = lane & 15, lq = lane >> 4;
  const int brow = blockIdx.y * 256, bcol = blockIdx.x * 256;
  const unsigned short* Ab = A + (size_t)brow * K;
  const unsigned short* Bb = Bm + (size_t)bcol * K;
  f32x4 acc[8][4] = {};
  const int nT = K >> 6;

  auto stage = [&](int kt, int buf) {
#pragma unroll
    for (int it = 0; it < 4; ++it) {
      int c = it * 512 + t;
      int row = c >> 3, pos = c & 7;
      int j = pos ^ (row & 7);
      gload_lds16(Ab + (size_t)row * K + kt * 64 + j * 8, (char*)&Al[buf][0] + c * 16);
    }
#pragma unroll
    for (int it = 0; it < 4; ++it) {
      int c = it * 512 + t;
      int row = c >> 3, pos = c & 7;
      int j = pos ^ (row & 7);
      gload_lds16(Bb + (size_t)row * K + kt * 64 + j * 8, (char*)&Bl[buf][0] + c * 16);
    }
  };

  stage(0, 0);
  stage(1, 1);
  for (int kt = 0; kt < nT; ++kt) {
    if (kt + 1 < nT) asm volatile("s_waitcnt vmcnt(8)" ::: "memory");
    else             asm volatile("s_waitcnt vmcnt(0)" ::: "memory");
    __builtin_amdgcn_s_barrier();      // all waves: tile kt landed
    __builtin_amdgcn_sched_barrier(0);
    const unsigned short* Abl = &Al[kt & 1][0];
    const unsigned short* Bbl = &Bl[kt & 1][0];
#pragma unroll
    for (int ks = 0; ks < 2; ++ks) {
      bf16x8 aF[8], bF[4];
      const int j = ks * 4 + lq;  // logical 16B chunk (k-offset lq*8 within ks*32)
#pragma unroll
      for (int m = 0; m < 8; ++m) {
        int row = wm * 128 + m * 16 + l15;
        aF[m] = *(const bf16x8*)&Abl[row * 64 + (j ^ (row & 7)) * 8];
      }
#pragma unroll
      for (int n = 0; n < 4; ++n) {
        int row = wn * 64 + n * 16 + l15;
        bF[n] = *(const bf16x8*)&Bbl[row * 64 + (j ^ (row & 7)) * 8];
      }
      __builtin_amdgcn_s_setprio(1);
#pragma unroll
      for (int m = 0; m < 8; ++m)
#pragma unroll
        for (int n = 0; n < 4; ++n)
          acc[m][n] = __builtin_amdgcn_mfma_f32_16x16x32_bf16(aF[m], bF[n], acc[m][n], 0, 0, 0);
      __builtin_amdgcn_s_setprio(0);
    }
    asm volatile("s_waitcnt lgkmcnt(0)" ::: "memory");
    __builtin_amdgcn_s_barrier();      // all waves done reading buf (kt&1)
    __builtin_amdgcn_sched_barrier(0);
    if (kt + 2 < nT) stage(kt + 2, kt & 1);  // safe: last read of this buf was tile kt
  }

  const int lr = lq * 4;
  if (BF16OUT) {
    unsigned short* C = (unsigned short*)Cout;
#pragma unroll
    for (int m = 0; m < 8; ++m) {
      int row = brow + wm * 128 + m * 16 + lr;
#pragma unroll
      for (int n = 0; n < 4; ++n) {
        int col = bcol + wn * 64 + n * 16 + l15;
#pragma unroll
        for (int i = 0; i < 4; ++i)
          C[(size_t)(row + i) * N + col] = f2bf(acc[m][n][i]);
      }
    }
  } else {
    float* C = (float*)Cout;
#pragma unroll
    for (int m = 0; m < 8; ++m) {
      int row = brow + wm * 128 + m * 16 + lr;
#pragma unroll
      for (int n = 0; n < 4; ++n) {
        int col = bcol + wn * 64 + n * 16 + l15;
#pragma unroll
        for (int i = 0; i < 4; ++i)
          C[(size_t)(row + i) * N + col] = acc[m][n][i];
      }
    }
  }
}

// ---------------- RoPE in place on QKV [4096][5120] ----------------
__global__ void rope_kernel(unsigned short* __restrict__ QKV, const float* __restrict__ cosT,
                            const float* __restrict__ sinT) {
  int rid = blockIdx.x;
  int s = rid & (Sn - 1);
  unsigned short* row = QKV + (size_t)rid * LDQKV;
  for (int p = threadIdx.x; p < 32 * 48; p += 256) {
    int h = p / 48, i = p % 48;
    int col = (h < NQn) ? h * HDn : KCOLo + (h - NQn) * HDn;
    float c = cosT[s * 48 + i], sn = sinT[s * 48 + i];
    float x1 = bf2f(row[col + i]), x2 = bf2f(row[col + i + 48]);
    row[col + i] = f2bf(x1 * c - x2 * sn);
    row[col + i + 48] = f2bf(x2 * c + x1 * sn);
  }
}

// ---------------- Flash attention (causal, GQA 3:1), QBLK=32/wave ----------------
// Swapped-operand QK^T (lane-local q). Each wave owns 32 q rows (2 subtiles of 16);
// kf/vf LDS fragments are read ONCE and feed both subtiles' MFMAs -> 2x FLOP per
// LDS byte vs QBLK=16 (the round-8 kernel was LDS-read-BW-bound).
// grid: (S/128, B*NQ); 256 thr = 4 waves; block covers 128 q rows.
__launch_bounds__(256, 2)
__global__ void attn_kernel(const unsigned short* __restrict__ QKV,
                            const unsigned short* __restrict__ VT,
                            unsigned short* __restrict__ O) {
  __shared__ __align__(16) char smem[81920];
  unsigned short* Klds = (unsigned short*)smem;            // [2][64*128]  32KB
  unsigned short* Vlds = (unsigned short*)(smem + 32768);  // [2][128*64]  32KB
  unsigned short* Plds = (unsigned short*)(smem + 65536);  // [4][2][16*64] 16KB
  const int t = threadIdx.x, lane = t & 63, w = t >> 6;
  const int bq = gridDim.x - 1 - blockIdx.x;  // heavy blocks dispatch first
  const int hid = blockIdx.y;
  const int b = hid / NQn, u = hid % NQn, kv = u / 3;
  const int l15 = lane & 15, lh = lane >> 4;
  const int q0 = bq * 128 + w * 32;  // wave's first q row

  bf16x8 qf[2][4];
#pragma unroll
  for (int qs = 0; qs < 2; ++qs) {
    int qrow = q0 + qs * 16 + l15;
    const unsigned short* qp = QKV + (size_t)(b * Sn + qrow) * LDQKV + u * HDn;
#pragma unroll
    for (int f = 0; f < 4; ++f) qf[qs][f] = *(const bf16x8*)(qp + f * 32 + lh * 8);
  }
  float m_l[2] = {-1e30f, -1e30f}, l_l[2] = {0.f, 0.f};
  f32x4 Oa[2][8] = {};  // Oa[qs][g][i] = O[hd=g*16+lh*4+i][q=l15] for subtile qs
  const float cscale = 0.08838834764831845f * 1.4426950408889634f;  // 1/sqrt(128)*log2e

  const unsigned short* Kg = QKV + (size_t)(b * Sn) * LDQKV + KCOLo + kv * HDn;
  const unsigned short* Vg = VT + (size_t)(b * NKVn + kv) * HDn * Sn;

  auto stageK = [&](int kt, int buf) {
#pragma unroll
    for (int iter = 0; iter < 4; ++iter) {
      int c = iter * 256 + t;
      int krow = c >> 4, pch = c & 15;
      int hch = (pch & 8) | ((pch & 7) ^ (krow & 7));
      gload_lds16(Kg + (size_t)(kt * 64 + krow) * LDQKV + hch * 8,
                  (char*)Klds + buf * 16384 + (iter * 256 + w * 64) * 16);
    }
  };
  auto stageV = [&](int kt, int buf) {
#pragma unroll
    for (int iter = 0; iter < 4; ++iter) {
      int c = iter * 256 + t;
      int hd = c >> 3, p = c & 7;
      int sch = p ^ (hd & 7);
      gload_lds16(Vg + (size_t)hd * Sn + kt * 64 + sch * 8,
                  (char*)Vlds + buf * 16384 + (iter * 256 + w * 64) * 16);
    }
  };

  const int nt = 2 * bq + 2;
  stageK(0, 0);
  stageV(0, 0);
  __syncthreads();  // drains vmcnt (barrier semantics)

  for (int kt = 0; kt < nt; ++kt) {
    const int cur = kt & 1;
    if (kt + 1 < nt) { stageK(kt + 1, cur ^ 1); stageV(kt + 1, cur ^ 1); }
    const unsigned short* Kb = Klds + cur * 8192;
    const unsigned short* Vb = Vlds + cur * 8192;
    // wave-level skip of fully-masked tiles (math no-op; must still hit barriers)
    if (kt * 64 <= q0 + 31) {
      // QK^T swapped: Sg[qs][g] = S[k=g*16+lh*4+i][q=l15 of subtile qs]
      f32x4 Sg[2][4] = {};
      __builtin_amdgcn_s_setprio(1);
#pragma unroll
      for (int g = 0; g < 4; ++g) {
        int kcol = g * 16 + l15;  // A-row = k
#pragma unroll
        for (int s = 0; s < 4; ++s) {
          int h = s * 4 + lh;
          int p = (h & 8) | ((h & 7) ^ (kcol & 7));
          bf16x8 kf = *(const bf16x8*)&Kb[kcol * 128 + p * 8];
          Sg[0][g] = __builtin_amdgcn_mfma_f32_16x16x32_bf16(kf, qf[0][s], Sg[0][g], 0, 0, 0);
          Sg[1][g] = __builtin_amdgcn_mfma_f32_16x16x32_bf16(kf, qf[1][s], Sg[1][g], 0, 0, 0);
        }
      }
      __builtin_amdgcn_s_setprio(0);
      const bool maskT = kt * 64 + 63 > q0;  // tile may cross the diagonal
#pragma unroll
      for (int qs = 0; qs < 2; ++qs) {
        float P[4][4];
        const int qin = q0 + qs * 16 + l15;
#pragma unroll
        for (int g = 0; g < 4; ++g)
#pragma unroll
          for (int i = 0; i < 4; ++i) {
            float sv = Sg[qs][g][i] * cscale;
            if (maskT && (kt * 64 + g * 16 + lh * 4 + i) > qin) sv = -1e30f;
            P[g][i] = sv;
          }
        float pmax = -1e30f;
#pragma unroll
        for (int g = 0; g < 4; ++g)
#pragma unroll
          for (int i = 0; i < 4; ++i) pmax = fmaxf(pmax, P[g][i]);
        pmax = fmaxf(pmax, __shfl_xor(pmax, 16, 64));
        pmax = fmaxf(pmax, __shfl_xor(pmax, 32, 64));
        float mn = fmaxf(m_l[qs], pmax);
        float rs = exp2f(m_l[qs] - mn);
        m_l[qs] = mn;
        float ps = 0.f;
#pragma unroll
        for (int g = 0; g < 4; ++g)
#pragma unroll
          for (int i = 0; i < 4; ++i) {
            float e = exp2f(P[g][i] - mn);
            P[g][i] = e;
            ps += e;
          }
        ps += __shfl_xor(ps, 16, 64);
        ps += __shfl_xor(ps, 32, 64);
        l_l[qs] = l_l[qs] * rs + ps;
#pragma unroll
        for (int g = 0; g < 8; ++g)
#pragma unroll
          for (int i = 0; i < 4; ++i) Oa[qs][g][i] *= rs;
        // P -> per-wave LDS [q=l15][k], packed b64 writes, swizzled by ch^(q&7)
        unsigned short* pl = Plds + w * 2048 + qs * 1024;
#pragma unroll
        for (int g = 0; g < 4; ++g) {
          int ch = g * 2 + (lh >> 1);
          int pos = ch ^ (l15 & 7);
          u16x4 pk;
#pragma unroll
          for (int i = 0; i < 4; ++i) pk[i] = f2bf(P[g][i]);
          *(u16x4*)&pl[l15 * 64 + pos * 8 + (lh & 1) * 4] = pk;
        }
      }
      // PV swapped: Oa[qs][g] = mfma(V[hd][k], P[k][q]); vf read once per (kk,g)
      __builtin_amdgcn_s_setprio(1);
#pragma unroll
      for (int kk = 0; kk < 2; ++kk) {
        int ch = kk * 4 + lh;
        int ppos = ((ch ^ (l15 & 7)) & 7) * 8;
        bf16x8 pf0 = *(const bf16x8*)&Plds[w * 2048 + l15 * 64 + ppos];
        bf16x8 pf1 = *(const bf16x8*)&Plds[w * 2048 + 1024 + l15 * 64 + ppos];
#pragma unroll
        for (int g = 0; g < 8; ++g) {
          int hd = g * 16 + l15;
          int vpos = (ch ^ (hd & 7)) & 7;
          bf16x8 vf = *(const bf16x8*)&Vb[hd * 64 + vpos * 8];
          Oa[0][g] = __builtin_amdgcn_mfma_f32_16x16x32_bf16(vf, pf0, Oa[0][g], 0, 0, 0);
          Oa[1][g] = __builtin_amdgcn_mfma_f32_16x16x32_bf16(vf, pf1, Oa[1][g], 0, 0, 0);
        }
      }
      __builtin_amdgcn_s_setprio(0);
    }
    __syncthreads();  // all waves done with buf cur; next-tile loads drained
  }
  // Epilogue: O^T -> O through per-wave scratch in (dead) K/V LDS, coalesced store.
  // Each (q = lane>>1, a = lane&1) pair owns 64 hd values -> 8 x bf16x8 chunks.
  {
    unsigned short* sc = (unsigned short*)smem + w * 4352;  // [32 q][136 hd] padded
#pragma unroll
    for (int qs = 0; qs < 2; ++qs) {
      float inv = 1.0f / l_l[qs];
#pragma unroll
      for (int g = 0; g < 8; ++g)
#pragma unroll
        for (int i = 0; i < 4; ++i)
          sc[(qs * 16 + l15) * 136 + g * 16 + lh * 4 + i] = f2bf(Oa[qs][g][i] * inv);
    }
    int q = lane >> 1, a = lane & 1;
    int row = bq * 128 + w * 32 + q;
    unsigned short* op = O + (size_t)(b * Sn + row) * (NQn * HDn) + u * HDn;
    const unsigned short* scr = sc + q * 136 + a * 64;
#pragma unroll
    for (int j = 0; j < 8; ++j) {
      bf16x8 v = *(const bf16x8*)&scr[j * 8];
      *(bf16x8*)&op[a * 64 + j * 8] = v;
    }
  }
}

}  // namespace

extern "C" void kernel_launch(void* const* d_in, const int* in_sizes, int n_in,
                              void* d_out, int out_size, void* d_ws, size_t ws_size,
                              hipStream_t stream) {
  const float* hidden = (const float*)d_in[0];
  // d_in[1] = attention_mask (causal tril) -- implemented analytically
  const float* Wq = (const float*)d_in[2];
  const float* Wk = (const float*)d_in[3];
  const float* Wv = (const float*)d_in[4];
  const float* Wo = (const float*)d_in[5];
  float* out = (float*)d_out;

  // Workspace layout (aliased; same-stream ordering makes each alias safe):
  //   [0)           Xb   (25.2MB)  -- dead after GEMM1; Obuf aliases it
  //   [szXb)        Wqkv (31.5MB)  -- dead after GEMM1; Wob (18.9MB) + VT (8.4MB) alias it
  //   [szXb+szWqkv) QKV  (41.9MB)
  //   [+szQKV)      cosT/sinT (0.8MB)
  char* ws = (char*)d_ws;
  constexpr size_t szXb = (size_t)Bn * Sn * Hn * 2;             // 25165824
  constexpr size_t szWqkv = (size_t)LDQKV * Hn * 2;             // 31457280
  constexpr size_t szWo = (size_t)Hn * Hn * 2;                  // 18874368
  constexpr size_t szVT = (size_t)Bn * NKVn * HDn * Sn * 2;     // 8388608
  constexpr size_t szQKV = (size_t)Bn * Sn * LDQKV * 2;         // 41943040
  constexpr size_t szTab = (size_t)Sn * 48 * 4;                 // 393216
  static_assert(szWo + szVT <= szWqkv, "Wob+VT must fit in Wqkv region");
  constexpr size_t szTotal = szXb + szWqkv + szQKV + 2 * szTab; // 99352576
  if (ws_size < szTotal) return;  // fail cleanly, don't fault

  unsigned short* Xb = (unsigned short*)(ws);
  unsigned short* Obuf = Xb;                                  // alias
  unsigned short* Wqkv = (unsigned short*)(ws + szXb);
  unsigned short* Wob = Wqkv;                                 // alias (after GEMM1)
  unsigned short* VT = (unsigned short*)(ws + szXb + szWo);   // alias (after GEMM1)
  unsigned short* QKV = (unsigned short*)(ws + szXb + szWqkv);
  float* cosT = (float*)(ws + szXb + szWqkv + szQKV);
  float* sinT = (float*)(ws + szXb + szWqkv + szQKV + szTab);

  build_rope_tab<<<(Sn * 48 + 255) / 256, 256, 0, stream>>>(cosT, sinT);
  cvt_f32_bf16<<<3072, 256, 0, stream>>>(hidden, Xb, Bn * Sn * Hn);
  transpose_cvt<<<dim3(96, 96), 256, 0, stream>>>(Wq, Wqkv, Hn, NQn * HDn);
  transpose_cvt<<<dim3(32, 96), 256, 0, stream>>>(Wk, Wqkv + (size_t)KCOLo * Hn, Hn, NKVn * HDn);
  transpose_cvt<<<dim3(32, 96), 256, 0, stream>>>(Wv, Wqkv + (size_t)VCOLo * Hn, Hn, NKVn * HDn);
  gemm256<1><<<dim3(LDQKV / 256, (Bn * Sn) / 256), 512, 0, stream>>>(Xb, Wqkv, QKV,
                                                                     Bn * Sn, LDQKV, Hn);
  // Wqkv and Xb are now dead; reuse their space.
  transpose_cvt<<<dim3(96, 96), 256, 0, stream>>>(Wo, Wob, Hn, Hn);
  transpose_v<<<dim3(Sn / 32, Bn * NKVn * HDn / 32), 256, 0, stream>>>(QKV, VT);
  rope_kernel<<<Bn * Sn, 256, 0, stream>>>(QKV, cosT, sinT);
  attn_kernel<<<dim3(Sn / 128, Bn * NQn), 256, 0, stream>>>(QKV, VT, Obuf);
  gemm256<0><<<dim3(Hn / 256, (Bn * Sn) / 256), 512, 0, stream>>>(Obuf, Wob, out,
                                                                  Bn * Sn, Hn, Hn);
}

// Round 13
// 642.047 us; speedup vs baseline: 1.0525x; 1.0519x over previous
//
#include <hip/hip_runtime.h>
#include <hip/hip_bf16.h>
#include <cstdint>

namespace {

constexpr int Bn = 2, Sn = 2048, Hn = 3072, NQn = 24, NKVn = 8, HDn = 128;
constexpr int LDQKV = NQn * HDn + 2 * NKVn * HDn;  // 5120
constexpr int KCOLo = NQn * HDn;                   // 3072
constexpr int VCOLo = KCOLo + NKVn * HDn;          // 4096

typedef __attribute__((ext_vector_type(8))) __bf16 bf16x8;
typedef __attribute__((ext_vector_type(4))) float f32x4;
typedef __attribute__((ext_vector_type(4))) unsigned short u16x4;

__device__ __forceinline__ unsigned short f2bf(float f) {
  union { float f; unsigned u; } v; v.f = f;
  return (unsigned short)((v.u + 0x7fffu + ((v.u >> 16) & 1u)) >> 16);
}
__device__ __forceinline__ float bf2f(unsigned short u) {
  union { unsigned u; float f; } v; v.u = ((unsigned)u) << 16;
  return v.f;
}
__device__ __forceinline__ void gload_lds16(const void* g, void* l) {
  __builtin_amdgcn_global_load_lds(
      (__attribute__((address_space(1))) void*)(uintptr_t)g,
      (__attribute__((address_space(3))) void*)(uintptr_t)l, 16, 0, 0);
}

// ---------------- RoPE cos/sin table: [S][48] each ----------------
__global__ void build_rope_tab(float* __restrict__ cosT, float* __restrict__ sinT) {
  int idx = blockIdx.x * 256 + threadIdx.x;
  if (idx >= Sn * 48) return;
  int s = idx / 48, i = idx % 48;
  float invf = exp2f(-(float)i * (13.287712379549449f / 48.f));
  float f = (float)s * invf;
  cosT[idx] = cosf(f);
  sinT[idx] = sinf(f);
}

// ---------------- f32 -> bf16 elementwise ----------------
__global__ void cvt_f32_bf16(const float* __restrict__ in, unsigned short* __restrict__ out, int n) {
  int i = (blockIdx.x * 256 + threadIdx.x) * 4;
  int stride = gridDim.x * 256 * 4;
  for (; i < n; i += stride) {
    float4 v = *(const float4*)&in[i];
    u16x4 o;
    o[0] = f2bf(v.x); o[1] = f2bf(v.y); o[2] = f2bf(v.z); o[3] = f2bf(v.w);
    *(u16x4*)&out[i] = o;
  }
}

// ---------------- transpose + convert: in f32 [K][N] -> out bf16 [N][K] ----------------
__global__ void transpose_cvt(const float* __restrict__ in, unsigned short* __restrict__ out,
                              int K, int N) {
  __shared__ float tile[32][33];
  int bx = blockIdx.x * 32;  // N
  int by = blockIdx.y * 32;  // K
  int tx = threadIdx.x & 31, ty = threadIdx.x >> 5;
#pragma unroll
  for (int r = ty; r < 32; r += 8)
    tile[r][tx] = in[(size_t)(by + r) * N + bx + tx];
  __syncthreads();
#pragma unroll
  for (int r = ty; r < 32; r += 8)
    out[(size_t)(bx + r) * K + by + tx] = f2bf(tile[tx][r]);
}

// ---------------- V pre-transpose: QKV V-cols -> VT[(b*NKV+kv)*HD + hd][s] ----------------
__global__ void transpose_v(const unsigned short* __restrict__ QKV, unsigned short* __restrict__ VT) {
  __shared__ unsigned short tile[32][33];
  int s0 = blockIdx.x * 32;
  int b = blockIdx.y >> 5;
  int vc0 = (blockIdx.y & 31) * 32;  // 0..992 within the 1024 V cols of batch b
  int tx = threadIdx.x & 31, ty = threadIdx.x >> 5;
#pragma unroll
  for (int r = ty; r < 32; r += 8)
    tile[r][tx] = QKV[(size_t)(b * Sn + s0 + r) * LDQKV + VCOLo + vc0 + tx];
  __syncthreads();
#pragma unroll
  for (int r = ty; r < 32; r += 8)
    VT[(size_t)(b * (NKVn * HDn) + vc0 + r) * Sn + s0 + tx] = tile[tx][r];
}

// ---------------- 256x256 TN GEMM, BK=64, 8 waves, counted-vmcnt pipeline ----------------
template <int BF16OUT>
__launch_bounds__(512, 1)
__global__ void gemm256(const unsigned short* __restrict__ A, const unsigned short* __restrict__ Bm,
                        void* __restrict__ Cout, int M, int N, int K) {
  __shared__ unsigned short Al[2][256 * 64];
  __shared__ unsigned short Bl[2][256 * 64];
  const int t = threadIdx.x;
  const int lane = t & 63;
  const int w = t >> 6;              // 8 waves: 2 (M) x 4 (N)
  const int wm = w >> 2, wn = w & 3;
  const int l15 = lane & 15, lq = lane >> 4;
  const int brow = blockIdx.y * 256, bcol = blockIdx.x * 256;
  const unsigned short* Ab = A + (size_t)brow * K;
  const unsigned short* Bb = Bm + (size_t)bcol * K;
  f32x4 acc[8][4] = {};
  const int nT = K >> 6;

  auto stage = [&](int kt, int buf) {
#pragma unroll
    for (int it = 0; it < 4; ++it) {
      int c = it * 512 + t;
      int row = c >> 3, pos = c & 7;
      int j = pos ^ (row & 7);
      gload_lds16(Ab + (size_t)row * K + kt * 64 + j * 8, (char*)&Al[buf][0] + c * 16);
    }
#pragma unroll
    for (int it = 0; it < 4; ++it) {
      int c = it * 512 + t;
      int row = c >> 3, pos = c & 7;
      int j = pos ^ (row & 7);
      gload_lds16(Bb + (size_t)row * K + kt * 64 + j * 8, (char*)&Bl[buf][0] + c * 16);
    }
  };

  stage(0, 0);
  stage(1, 1);
  for (int kt = 0; kt < nT; ++kt) {
    if (kt + 1 < nT) asm volatile("s_waitcnt vmcnt(8)" ::: "memory");
    else             asm volatile("s_waitcnt vmcnt(0)" ::: "memory");
    __builtin_amdgcn_s_barrier();      // all waves: tile kt landed
    __builtin_amdgcn_sched_barrier(0);
    const unsigned short* Abl = &Al[kt & 1][0];
    const unsigned short* Bbl = &Bl[kt & 1][0];
#pragma unroll
    for (int ks = 0; ks < 2; ++ks) {
      bf16x8 aF[8], bF[4];
      const int j = ks * 4 + lq;  // logical 16B chunk (k-offset lq*8 within ks*32)
#pragma unroll
      for (int m = 0; m < 8; ++m) {
        int row = wm * 128 + m * 16 + l15;
        aF[m] = *(const bf16x8*)&Abl[row * 64 + (j ^ (row & 7)) * 8];
      }
#pragma unroll
      for (int n = 0; n < 4; ++n) {
        int row = wn * 64 + n * 16 + l15;
        bF[n] = *(const bf16x8*)&Bbl[row * 64 + (j ^ (row & 7)) * 8];
      }
      __builtin_amdgcn_s_setprio(1);
#pragma unroll
      for (int m = 0; m < 8; ++m)
#pragma unroll
        for (int n = 0; n < 4; ++n)
          acc[m][n] = __builtin_amdgcn_mfma_f32_16x16x32_bf16(aF[m], bF[n], acc[m][n], 0, 0, 0);
      __builtin_amdgcn_s_setprio(0);
    }
    asm volatile("s_waitcnt lgkmcnt(0)" ::: "memory");
    __builtin_amdgcn_s_barrier();      // all waves done reading buf (kt&1)
    __builtin_amdgcn_sched_barrier(0);
    if (kt + 2 < nT) stage(kt + 2, kt & 1);  // safe: last read of this buf was tile kt
  }

  const int lr = lq * 4;
  if (BF16OUT) {
    unsigned short* C = (unsigned short*)Cout;
#pragma unroll
    for (int m = 0; m < 8; ++m) {
      int row = brow + wm * 128 + m * 16 + lr;
#pragma unroll
      for (int n = 0; n < 4; ++n) {
        int col = bcol + wn * 64 + n * 16 + l15;
#pragma unroll
        for (int i = 0; i < 4; ++i)
          C[(size_t)(row + i) * N + col] = f2bf(acc[m][n][i]);
      }
    }
  } else {
    float* C = (float*)Cout;
#pragma unroll
    for (int m = 0; m < 8; ++m) {
      int row = brow + wm * 128 + m * 16 + lr;
#pragma unroll
      for (int n = 0; n < 4; ++n) {
        int col = bcol + wn * 64 + n * 16 + l15;
#pragma unroll
        for (int i = 0; i < 4; ++i)
          C[(size_t)(row + i) * N + col] = acc[m][n][i];
      }
    }
  }
}

// ---------------- RoPE in place on QKV [4096][5120] ----------------
__global__ void rope_kernel(unsigned short* __restrict__ QKV, const float* __restrict__ cosT,
                            const float* __restrict__ sinT) {
  int rid = blockIdx.x;
  int s = rid & (Sn - 1);
  unsigned short* row = QKV + (size_t)rid * LDQKV;
  for (int p = threadIdx.x; p < 32 * 48; p += 256) {
    int h = p / 48, i = p % 48;
    int col = (h < NQn) ? h * HDn : KCOLo + (h - NQn) * HDn;
    float c = cosT[s * 48 + i], sn = sinT[s * 48 + i];
    float x1 = bf2f(row[col + i]), x2 = bf2f(row[col + i + 48]);
    row[col + i] = f2bf(x1 * c - x2 * sn);
    row[col + i + 48] = f2bf(x2 * c + x1 * sn);
  }
}

// ---------------- Flash attention (causal, GQA 3:1), 8 waves sharing K/V staging ----
// 512 thr = 8 waves, each wave 16 q-rows (block = 128 q rows). K/V staged once per
// block per tile (amortized over 8 waves); 2 blocks/CU -> 4 waves/SIMD (2x latency
// hiding vs round-8/11's 2/SIMD). Swapped-operand QK^T (lane-local q), defer-max
// rescale (T13), v_cvt_pk_bf16_f32 P packing (T12).
// grid: (S/128, B*NQ).
__launch_bounds__(512, 4)
__global__ void attn_kernel(const unsigned short* __restrict__ QKV,
                            const unsigned short* __restrict__ VT,
                            unsigned short* __restrict__ O) {
  __shared__ __align__(16) char smem[81920];
  unsigned short* Klds = (unsigned short*)smem;            // [2][64*128]  32KB
  unsigned short* Vlds = (unsigned short*)(smem + 32768);  // [2][128*64]  32KB
  unsigned short* Plds = (unsigned short*)(smem + 65536);  // [8][16*64]   16KB
  const int t = threadIdx.x, lane = t & 63, w = t >> 6;
  const int bq = gridDim.x - 1 - blockIdx.x;  // heavy blocks dispatch first
  const int hid = blockIdx.y;
  const int b = hid / NQn, u = hid % NQn, kv = u / 3;
  const int l15 = lane & 15, lh = lane >> 4;
  const int q0 = bq * 128 + w * 16;  // wave's first q row

  bf16x8 qf[4];
  {
    int qrow = q0 + l15;
    const unsigned short* qp = QKV + (size_t)(b * Sn + qrow) * LDQKV + u * HDn;
#pragma unroll
    for (int f = 0; f < 4; ++f) qf[f] = *(const bf16x8*)(qp + f * 32 + lh * 8);
  }
  float m_l = -1e30f, l_l = 0.f;
  f32x4 Oa[8] = {};  // Oa[g][i] = O[hd=g*16+lh*4+i][q=l15]
  const float cscale = 0.08838834764831845f * 1.4426950408889634f;  // 1/sqrt(128)*log2e

  const unsigned short* Kg = QKV + (size_t)(b * Sn) * LDQKV + KCOLo + kv * HDn;
  const unsigned short* Vg = VT + (size_t)(b * NKVn + kv) * HDn * Sn;

  auto stageK = [&](int kt, int buf) {
#pragma unroll
    for (int it = 0; it < 2; ++it) {
      int c = it * 512 + t;
      int krow = c >> 4, pch = c & 15;
      int hch = (pch & 8) | ((pch & 7) ^ (krow & 7));
      gload_lds16(Kg + (size_t)(kt * 64 + krow) * LDQKV + hch * 8,
                  (char*)Klds + buf * 16384 + c * 16);
    }
  };
  auto stageV = [&](int kt, int buf) {
#pragma unroll
    for (int it = 0; it < 2; ++it) {
      int c = it * 512 + t;
      int hd = c >> 3, p = c & 7;
      int sch = p ^ (hd & 7);
      gload_lds16(Vg + (size_t)hd * Sn + kt * 64 + sch * 8,
                  (char*)Vlds + buf * 16384 + c * 16);
    }
  };

  const int nt = 2 * bq + 2;
  stageK(0, 0);
  stageV(0, 0);
  __syncthreads();  // drains vmcnt (barrier semantics)

  for (int kt = 0; kt < nt; ++kt) {
    const int cur = kt & 1;
    if (kt + 1 < nt) { stageK(kt + 1, cur ^ 1); stageV(kt + 1, cur ^ 1); }
    const unsigned short* Kb = Klds + cur * 8192;
    const unsigned short* Vb = Vlds + cur * 8192;
    // wave-level skip of fully-masked tiles (math no-op; must still hit barriers)
    if (kt * 64 <= q0 + 15) {
      // QK^T swapped: Sg[g] = S[k=g*16+lh*4+i][q=l15]
      f32x4 Sg[4] = {};
      __builtin_amdgcn_s_setprio(1);
#pragma unroll
      for (int g = 0; g < 4; ++g) {
        int kcol = g * 16 + l15;  // A-row = k
#pragma unroll
        for (int s = 0; s < 4; ++s) {
          int h = s * 4 + lh;
          int p = (h & 8) | ((h & 7) ^ (kcol & 7));
          bf16x8 kf = *(const bf16x8*)&Kb[kcol * 128 + p * 8];
          Sg[g] = __builtin_amdgcn_mfma_f32_16x16x32_bf16(kf, qf[s], Sg[g], 0, 0, 0);
        }
      }
      __builtin_amdgcn_s_setprio(0);
      float P[4][4];
      const bool maskT = kt * 64 + 63 > q0;  // tile may cross the diagonal
      const int qin = q0 + l15;
#pragma unroll
      for (int g = 0; g < 4; ++g)
#pragma unroll
        for (int i = 0; i < 4; ++i) {
          float sv = Sg[g][i] * cscale;
          if (maskT && (kt * 64 + g * 16 + lh * 4 + i) > qin) sv = -1e30f;
          P[g][i] = sv;
        }
      float pmax = -1e30f;
#pragma unroll
      for (int g = 0; g < 4; ++g)
#pragma unroll
        for (int i = 0; i < 4; ++i) pmax = fmaxf(pmax, P[g][i]);
      pmax = fmaxf(pmax, __shfl_xor(pmax, 16, 64));
      pmax = fmaxf(pmax, __shfl_xor(pmax, 32, 64));
      // T13 defer-max: skip rescale while max growth <= 8 (P bounded by 2^8)
      if (__any(pmax > m_l + 8.0f)) {
        float mn = fmaxf(m_l, pmax);
        float rs = exp2f(m_l - mn);
        m_l = mn;
        l_l *= rs;
#pragma unroll
        for (int g = 0; g < 8; ++g)
#pragma unroll
          for (int i = 0; i < 4; ++i) Oa[g][i] *= rs;
      }
      float ps = 0.f;
#pragma unroll
      for (int g = 0; g < 4; ++g)
#pragma unroll
        for (int i = 0; i < 4; ++i) {
          float e = exp2f(P[g][i] - m_l);
          P[g][i] = e;
          ps += e;
        }
      ps += __shfl_xor(ps, 16, 64);
      ps += __shfl_xor(ps, 32, 64);
      l_l += ps;
      // P -> per-wave LDS [q=l15][k], cvt_pk packed b64 writes, swizzled by ch^(q&7)
      unsigned short* pl = Plds + w * 1024;
#pragma unroll
      for (int g = 0; g < 4; ++g) {
        int ch = g * 2 + (lh >> 1);
        int pos = ch ^ (l15 & 7);
        union { unsigned u2[2]; u16x4 v4; } pk;
        asm("v_cvt_pk_bf16_f32 %0, %1, %2" : "=v"(pk.u2[0]) : "v"(P[g][0]), "v"(P[g][1]));
        asm("v_cvt_pk_bf16_f32 %0, %1, %2" : "=v"(pk.u2[1]) : "v"(P[g][2]), "v"(P[g][3]));
        *(u16x4*)&pl[l15 * 64 + pos * 8 + (lh & 1) * 4] = pk.v4;
      }
      // PV swapped: Oa[g] = mfma(V[hd][k], P[k][q]) -> D[hd][q]
      __builtin_amdgcn_s_setprio(1);
#pragma unroll
      for (int kk = 0; kk < 2; ++kk) {
        int ch = kk * 4 + lh;
        bf16x8 pf = *(const bf16x8*)&pl[l15 * 64 + ((ch ^ (l15 & 7)) & 7) * 8];
#pragma unroll
        for (int g = 0; g < 8; ++g) {
          int hd = g * 16 + l15;
          int vpos = (ch ^ (hd & 7)) & 7;
          bf16x8 vf = *(const bf16x8*)&Vb[hd * 64 + vpos * 8];
          Oa[g] = __builtin_amdgcn_mfma_f32_16x16x32_bf16(vf, pf, Oa[g], 0, 0, 0);
        }
      }
      __builtin_amdgcn_s_setprio(0);
    }
    __syncthreads();  // all waves done with buf cur; next-tile loads drained
  }
  // Epilogue: O^T -> O through per-wave scratch in (dead) K/V LDS, coalesced store.
  {
    unsigned short* sc = (unsigned short*)smem + w * 2176;  // [16 q][136 hd] padded
    float inv = 1.0f / l_l;
#pragma unroll
    for (int g = 0; g < 8; ++g)
#pragma unroll
      for (int i = 0; i < 4; ++i)
        sc[l15 * 136 + g * 16 + lh * 4 + i] = f2bf(Oa[g][i] * inv);
    int q = lane >> 2, a = lane & 3;
    int row = q0 + q;
    unsigned short* op = O + (size_t)(b * Sn + row) * (NQn * HDn) + u * HDn;
    const unsigned short* scr = sc + q * 136;
#pragma unroll
    for (int j = 0; j < 4; ++j) {
      bf16x8 v = *(const bf16x8*)&scr[a * 8 + j * 32];
      *(bf16x8*)&op[a * 8 + j * 32] = v;
    }
  }
}

}  // namespace

extern "C" void kernel_launch(void* const* d_in, const int* in_sizes, int n_in,
                              void* d_out, int out_size, void* d_ws, size_t ws_size,
                              hipStream_t stream) {
  const float* hidden = (const float*)d_in[0];
  // d_in[1] = attention_mask (causal tril) -- implemented analytically
  const float* Wq = (const float*)d_in[2];
  const float* Wk = (const float*)d_in[3];
  const float* Wv = (const float*)d_in[4];
  const float* Wo = (const float*)d_in[5];
  float* out = (float*)d_out;

  // Workspace layout (aliased; same-stream ordering makes each alias safe):
  //   [0)           Xb   (25.2MB)  -- dead after GEMM1; Obuf aliases it
  //   [szXb)        Wqkv (31.5MB)  -- dead after GEMM1; Wob (18.9MB) + VT (8.4MB) alias it
  //   [szXb+szWqkv) QKV  (41.9MB)
  //   [+szQKV)      cosT/sinT (0.8MB)
  char* ws = (char*)d_ws;
  constexpr size_t szXb = (size_t)Bn * Sn * Hn * 2;             // 25165824
  constexpr size_t szWqkv = (size_t)LDQKV * Hn * 2;             // 31457280
  constexpr size_t szWo = (size_t)Hn * Hn * 2;                  // 18874368
  constexpr size_t szVT = (size_t)Bn * NKVn * HDn * Sn * 2;     // 8388608
  constexpr size_t szQKV = (size_t)Bn * Sn * LDQKV * 2;         // 41943040
  constexpr size_t szTab = (size_t)Sn * 48 * 4;                 // 393216
  static_assert(szWo + szVT <= szWqkv, "Wob+VT must fit in Wqkv region");
  constexpr size_t szTotal = szXb + szWqkv + szQKV + 2 * szTab; // 99352576
  if (ws_size < szTotal) return;  // fail cleanly, don't fault

  unsigned short* Xb = (unsigned short*)(ws);
  unsigned short* Obuf = Xb;                                  // alias
  unsigned short* Wqkv = (unsigned short*)(ws + szXb);
  unsigned short* Wob = Wqkv;                                 // alias (after GEMM1)
  unsigned short* VT = (unsigned short*)(ws + szXb + szWo);   // alias (after GEMM1)
  unsigned short* QKV = (unsigned short*)(ws + szXb + szWqkv);
  float* cosT = (float*)(ws + szXb + szWqkv + szQKV);
  float* sinT = (float*)(ws + szXb + szWqkv + szQKV + szTab);

  build_rope_tab<<<(Sn * 48 + 255) / 256, 256, 0, stream>>>(cosT, sinT);
  cvt_f32_bf16<<<3072, 256, 0, stream>>>(hidden, Xb, Bn * Sn * Hn);
  transpose_cvt<<<dim3(96, 96), 256, 0, stream>>>(Wq, Wqkv, Hn, NQn * HDn);
  transpose_cvt<<<dim3(32, 96), 256, 0, stream>>>(Wk, Wqkv + (size_t)KCOLo * Hn, Hn, NKVn * HDn);
  transpose_cvt<<<dim3(32, 96), 256, 0, stream>>>(Wv, Wqkv + (size_t)VCOLo * Hn, Hn, NKVn * HDn);
  gemm256<1><<<dim3(LDQKV / 256, (Bn * Sn) / 256), 512, 0, stream>>>(Xb, Wqkv, QKV,
                                                                     Bn * Sn, LDQKV, Hn);
  // Wqkv and Xb are now dead; reuse their space.
  transpose_cvt<<<dim3(96, 96), 256, 0, stream>>>(Wo, Wob, Hn, Hn);
  transpose_v<<<dim3(Sn / 32, Bn * NKVn * HDn / 32), 256, 0, stream>>>(QKV, VT);
  rope_kernel<<<Bn * Sn, 256, 0, stream>>>(QKV, cosT, sinT);
  attn_kernel<<<dim3(Sn / 128, Bn * NQn), 512, 0, stream>>>(QKV, VT, Obuf);
  gemm256<0><<<dim3(Hn / 256, (Bn * Sn) / 256), 512, 0, stream>>>(Obuf, Wob, out,
                                                                  Bn * Sn, Hn, Hn);
}